// Round 8
// baseline (626.554 us; speedup 1.0000x reference)
//
#include <hip/hip_runtime.h>
#include <math.h>

// Problem constants (from reference)
#define N        8192
#define C        128
#define E_TOTAL  262144
#define WPR      256          // bitmap words per row = N/32
#define INV_TEMP 2.0f         // 1/0.5
#define STEPS    10
#define S_ELL    96           // max dedup'd neighbors per row (Poisson(~32) tail safe)
#define PGRID    512          // persistent kernel blocks (2/CU, capacity >=4/CU)
#define RPB      16           // rows per block = N / PGRID
#define ITEMS_PB 528          // (E_TOTAL + N) / PGRID
#define ZROW     N            // zero row in bf16 buffers (row N kept zero)

// ---- workspace layout (bytes) ----  (NO aliasing this time)
#define OFF_DINV    1024                          // float dinvs[N]   32 KB
#define OFF_CNT     (OFF_DINV + 32768)            // int   cnt[N]     32 KB
#define OFF_PART    (OFF_CNT + 32768)             // float part[512]
#define OFF_ELL     (OFF_PART + 4096)             // int   ellc[N*96] 3 MB
#define OFF_BARS    (OFF_ELL + N * S_ELL * 4)     // int   bars[...]  (zeroed)
#define BARS_BYTES  4096
#define OFF_BITMAP  (OFF_BARS + BARS_BYTES)       // 8 MB (zeroed each call)
#define BITMAP_BYTES (N * WPR * 4)
#define OFF_BUFA    (OFF_BITMAP + BITMAP_BYTES)   // bf16 (N+1)*C  (row N zeroed)
#define OFF_BUFB    (OFF_BUFA + (N + 1) * C * 2)  // bf16 (N+1)*C  (row N zeroed)
// bars indices: [s*16+g] lvl1 (s<10,g<16), [160+s] lvl2 root, [176] done-counter

typedef unsigned int   uint;
typedef unsigned short ushort;

__device__ __forceinline__ float bflo(uint u) { return __uint_as_float(u << 16); }
__device__ __forceinline__ float bfhi(uint u) { return __uint_as_float(u & 0xffff0000u); }
__device__ __forceinline__ ushort f2bf(float f) {   // RNE
    uint u = __float_as_uint(f);
    return (ushort)((u + 0x7fffu + ((u >> 16) & 1u)) >> 16);
}
__device__ __forceinline__ float dot_u(uint a, uint b) {
    return bflo(a) * bflo(b) + bfhi(a) * bfhi(b);
}
__device__ __forceinline__ float log_sigmoid(float z) {
    return fminf(z, 0.0f) - log1pf(expf(-fabsf(z)));
}

__global__ void scatter_edges_kernel(const int* __restrict__ ei,
                                     unsigned int* __restrict__ bm) {
    int e = blockIdx.x * blockDim.x + threadIdx.x;
    if (e >= E_TOTAL) return;
    int s = ei[e];
    int t = ei[E_TOTAL + e];
    atomicOr(&bm[s * WPR + (t >> 5)], 1u << (t & 31));
}

// One-time: bitmap -> ELL col list (ZROW-padded to x8) + true cnt + d^-1/2
__global__ void build_ell_kernel(const unsigned int* __restrict__ bm,
                                 int* __restrict__ cnt,
                                 int* __restrict__ ellc,
                                 float* __restrict__ dinvs) {
    int row = blockIdx.x;
    int lane = threadIdx.x;  // one wave; each lane owns 4 consecutive words
    const unsigned int* p = bm + row * WPR;
    unsigned int w[4];
    int c = 0;
    for (int i = 0; i < 4; ++i) { w[i] = p[lane * 4 + i]; c += __popc(w[i]); }
    int inc = c;
    for (int off = 1; off < 64; off <<= 1) {
        int v = __shfl_up(inc, off, 64);
        if (lane >= off) inc += v;
    }
    int pos = inc - c;
    int total = __shfl(inc, 63, 64);
    for (int i = 0; i < 4; ++i) {
        unsigned int word = w[i];
        int jbase = (lane * 4 + i) << 5;
        while (word) {
            int b = __ffs(word) - 1;
            word &= word - 1;
            if (pos < S_ELL) ellc[row * S_ELL + pos] = jbase + b;
            ++pos;
        }
    }
    int ncap = (total < S_ELL) ? total : S_ELL;
    int npad = (ncap + 7) & ~7;        // <= 96, fits in stride
    if (lane < npad - ncap)            // pad with pointer to the zero row
        ellc[row * S_ELL + ncap + lane] = ZROW;
    if (lane == 0) {
        cnt[row] = ncap;
        dinvs[row] = rsqrtf((float)total);   // deg >= 1 (self-loops)
    }
}

// Two-level grid barrier: 16 groups x 32 blocks -> 1 root per step.
__device__ __forceinline__ void grid_barrier(int* bars, int s) {
    __syncthreads();
    if (threadIdx.x == 0) {
        __threadfence();                        // release (agent scope)
        int g = blockIdx.x >> 5;                // 16 groups of 32 blocks
        int r = atomicAdd(&bars[s * 16 + g], 1);
        if (r == 31) atomicAdd(&bars[160 + s], 1);
        while (__hip_atomic_load(&bars[160 + s], __ATOMIC_RELAXED,
                                 __HIP_MEMORY_SCOPE_AGENT) < 16)
            __builtin_amdgcn_s_sleep(2);
    }
    __syncthreads();
    __threadfence();                            // acquire (all threads)
}

// Persistent kernel: 10 diffusion steps + fused pos/neg loss + final reduce.
// w_{s+1} = D^-1 A w_s  (unweighted neighbor sum, writer-side scale);
// step 0: gather weight d^-1/2[j] from fp32 input; step 9 writer-scale d^-1/2[row].
__global__ __launch_bounds__(256, 4) void fused_kernel(
        const int* __restrict__ cnt, const int* __restrict__ ellc,
        const float* __restrict__ dinvs, const float* __restrict__ x_in,
        const int* __restrict__ ei, const int* __restrict__ ridx,
        ushort* __restrict__ bufA, ushort* __restrict__ bufB,
        int* __restrict__ bars, float* __restrict__ part,
        float* __restrict__ out) {
    __shared__ int   scol[RPB * S_ELL];
    __shared__ int   sn[RPB];
    __shared__ float sid[RPB];   // 1/deg
    __shared__ float sds[RPB];   // d^-1/2
    __shared__ float red[4];
    __shared__ int   slast;

    const int b    = blockIdx.x;
    const int tid  = threadIdx.x;
    const int wid  = tid >> 6;
    const int lane = tid & 63;
    const int qw   = lane >> 4;   // quarter -> neighbor slot
    const int l16  = lane & 15;   // 8 channels per lane

    // stage ELL cols (incl. ZROW padding) for this block's 16 rows, once
    for (int i = tid; i < RPB * S_ELL; i += 256)
        scol[i] = ellc[b * RPB * S_ELL + i];
    if (tid < RPB) {
        int row = b * RPB + tid;
        sn[tid] = cnt[row];
        float ds = dinvs[row];
        sds[tid] = ds;
        sid[tid] = ds * ds;
    }
    __syncthreads();

    // ---- 10 diffusion steps ----
    for (int s = 0; s < STEPS; ++s) {
        const ushort* xin = (s & 1) ? bufA : bufB;   // valid for s>=1
        ushort*       yo  = (s & 1) ? bufB : bufA;
        for (int p = 0; p < 4; ++p) {
            int lr  = wid * 4 + p;
            int row = b * RPB + lr;
            int n   = sn[lr];
            const int* cr = scol + lr * S_ELL;
            float a0=0.f,a1=0.f,a2=0.f,a3=0.f,a4=0.f,a5=0.f,a6=0.f,a7=0.f;
            if (s == 0) {
                // x_in has no zero row: mask tail with (i<n) -> self col, weight 0
                for (int k = 0; k < n; k += 8) {
                    int i0 = k + qw, i1 = k + 4 + qw;
                    int   c0 = (i0 < n) ? cr[i0] : row;
                    int   c1 = (i1 < n) ? cr[i1] : row;
                    float w0 = (i0 < n) ? dinvs[c0] : 0.0f;
                    float w1 = (i1 < n) ? dinvs[c1] : 0.0f;
                    const float* r0 = x_in + c0 * C + l16 * 8;
                    const float* r1 = x_in + c1 * C + l16 * 8;
                    float4 ua = *(const float4*)r0, ub = *(const float4*)(r0 + 4);
                    float4 va = *(const float4*)r1, vb = *(const float4*)(r1 + 4);
                    a0 += w0 * ua.x + w1 * va.x;  a1 += w0 * ua.y + w1 * va.y;
                    a2 += w0 * ua.z + w1 * va.z;  a3 += w0 * ua.w + w1 * va.w;
                    a4 += w0 * ub.x + w1 * vb.x;  a5 += w0 * ub.y + w1 * vb.y;
                    a6 += w0 * ub.z + w1 * vb.z;  a7 += w0 * ub.w + w1 * vb.w;
                }
            } else {
                // ellc is ZROW-padded to x8; row ZROW of buffers is zero
                int npad = (n + 7) & ~7;
                for (int k = 0; k < npad; k += 8) {
                    int c0 = cr[k + qw];
                    int c1 = cr[k + 4 + qw];
                    uint4 u0 = *(const uint4*)(xin + c0 * C + l16 * 8);
                    uint4 u1 = *(const uint4*)(xin + c1 * C + l16 * 8);
                    a0 += bflo(u0.x) + bflo(u1.x);  a1 += bfhi(u0.x) + bfhi(u1.x);
                    a2 += bflo(u0.y) + bflo(u1.y);  a3 += bfhi(u0.y) + bfhi(u1.y);
                    a4 += bflo(u0.z) + bflo(u1.z);  a5 += bfhi(u0.z) + bfhi(u1.z);
                    a6 += bflo(u0.w) + bflo(u1.w);  a7 += bfhi(u0.w) + bfhi(u1.w);
                }
            }
            a0 += __shfl_xor(a0, 16, 64); a0 += __shfl_xor(a0, 32, 64);
            a1 += __shfl_xor(a1, 16, 64); a1 += __shfl_xor(a1, 32, 64);
            a2 += __shfl_xor(a2, 16, 64); a2 += __shfl_xor(a2, 32, 64);
            a3 += __shfl_xor(a3, 16, 64); a3 += __shfl_xor(a3, 32, 64);
            a4 += __shfl_xor(a4, 16, 64); a4 += __shfl_xor(a4, 32, 64);
            a5 += __shfl_xor(a5, 16, 64); a5 += __shfl_xor(a5, 32, 64);
            a6 += __shfl_xor(a6, 16, 64); a6 += __shfl_xor(a6, 32, 64);
            a7 += __shfl_xor(a7, 16, 64); a7 += __shfl_xor(a7, 32, 64);
            if (qw == 0) {
                float sc = (s == STEPS - 1) ? sds[lr] : sid[lr];
                uint4 o;
                o.x = (uint)f2bf(a0 * sc) | ((uint)f2bf(a1 * sc) << 16);
                o.y = (uint)f2bf(a2 * sc) | ((uint)f2bf(a3 * sc) << 16);
                o.z = (uint)f2bf(a4 * sc) | ((uint)f2bf(a5 * sc) << 16);
                o.w = (uint)f2bf(a6 * sc) | ((uint)f2bf(a7 * sc) << 16);
                *(uint4*)(yo + row * C + l16 * 8) = o;
            }
        }
        grid_barrier(bars, s);
    }

    // ---- fused loss over E pos edges + N neg rows (528 items / block) ----
    const ushort* emb = bufB;    // step 9 (odd) wrote bufB
    int g = lane >> 2;   // 16 items per wave-iteration
    int q = lane & 3;    // 4 lanes per item, 32 channels each
    float sum = 0.0f;
    int wbase = b * ITEMS_PB + wid * 132;
    for (int j = 0; j < 144; j += 16) {
        int rel = j + g;
        bool valid = rel < 132;
        int it = wbase + rel;
        bool pos = it < E_TOTAL;
        int s_ = 0, t_ = 0;
        if (valid) {
            if (pos) { s_ = ei[it]; t_ = ei[E_TOTAL + it]; }
            else     { int i2 = it - E_TOTAL; s_ = i2; t_ = ridx[i2]; }
        }
        const uint4* ps = (const uint4*)(emb + s_ * C + q * 32);
        const uint4* pt = (const uint4*)(emb + t_ * C + q * 32);
        uint4 s0 = ps[0], s1 = ps[1], s2 = ps[2], s3 = ps[3];
        uint4 t0 = pt[0], t1 = pt[1], t2 = pt[2], t3 = pt[3];
        float p = dot_u(s0.x, t0.x) + dot_u(s0.y, t0.y) + dot_u(s0.z, t0.z) + dot_u(s0.w, t0.w)
                + dot_u(s1.x, t1.x) + dot_u(s1.y, t1.y) + dot_u(s1.z, t1.z) + dot_u(s1.w, t1.w)
                + dot_u(s2.x, t2.x) + dot_u(s2.y, t2.y) + dot_u(s2.z, t2.z) + dot_u(s2.w, t2.w)
                + dot_u(s3.x, t3.x) + dot_u(s3.y, t3.y) + dot_u(s3.z, t3.z) + dot_u(s3.w, t3.w);
        p += __shfl_xor(p, 1, 64);
        p += __shfl_xor(p, 2, 64);
        if (q == 0 && valid) {
            float z  = pos ? p * INV_TEMP : -p * INV_TEMP;
            float sc = pos ? (-1.0f / (float)E_TOTAL) : (-1.0f / (float)N);
            sum += sc * log_sigmoid(z);
        }
    }
    sum += __shfl_xor(sum, 4, 64);
    sum += __shfl_xor(sum, 8, 64);
    sum += __shfl_xor(sum, 16, 64);
    sum += __shfl_xor(sum, 32, 64);
    if (lane == 0) red[wid] = sum;
    __syncthreads();
    if (tid == 0) {
        part[b] = (red[0] + red[1]) + (red[2] + red[3]);
        __threadfence();
        int r = atomicAdd(&bars[176], 1);
        slast = (r == PGRID - 1) ? 1 : 0;
    }
    __syncthreads();
    if (slast) {
        __threadfence();   // acquire: see all partials
        float v = part[tid] + part[tid + 256];
        v += __shfl_xor(v, 1, 64);
        v += __shfl_xor(v, 2, 64);
        v += __shfl_xor(v, 4, 64);
        v += __shfl_xor(v, 8, 64);
        v += __shfl_xor(v, 16, 64);
        v += __shfl_xor(v, 32, 64);
        if (lane == 0) red[wid] = v;
        __syncthreads();
        if (tid == 0) out[0] = (red[0] + red[1]) + (red[2] + red[3]);
    }
}

extern "C" void kernel_launch(void* const* d_in, const int* in_sizes, int n_in,
                              void* d_out, int out_size, void* d_ws, size_t ws_size,
                              hipStream_t stream) {
    (void)in_sizes; (void)n_in; (void)out_size; (void)ws_size;

    const float* emb_in = (const float*)d_in[0];
    const int*   ei     = (const int*)d_in[1];   // (2, E) flattened: src then dst
    const int*   ridx   = (const int*)d_in[2];
    float* out = (float*)d_out;

    char* ws = (char*)d_ws;
    float*        dinvs = (float*)(ws + OFF_DINV);
    int*          cnt   = (int*)(ws + OFF_CNT);
    float*        part  = (float*)(ws + OFF_PART);
    int*          ellc  = (int*)(ws + OFF_ELL);
    int*          bars  = (int*)(ws + OFF_BARS);
    unsigned int* bm    = (unsigned int*)(ws + OFF_BITMAP);
    ushort*       bufA  = (ushort*)(ws + OFF_BUFA);
    ushort*       bufB  = (ushort*)(ws + OFF_BUFB);

    hipMemsetAsync(bm, 0, BITMAP_BYTES, stream);
    hipMemsetAsync(bars, 0, BARS_BYTES, stream);
    // keep row ZROW of both bf16 buffers zero (ws is poisoned each call)
    hipMemsetAsync(bufA + (size_t)ZROW * C, 0, C * 2, stream);
    hipMemsetAsync(bufB + (size_t)ZROW * C, 0, C * 2, stream);

    scatter_edges_kernel<<<E_TOTAL / 256, 256, 0, stream>>>(ei, bm);
    build_ell_kernel<<<N, 64, 0, stream>>>(bm, cnt, ellc, dinvs);
    fused_kernel<<<PGRID, 256, 0, stream>>>(cnt, ellc, dinvs, emb_in, ei, ridx,
                                            bufA, bufB, bars, part, out);
}

// Round 10
// 181.613 us; speedup vs baseline: 3.4499x; 3.4499x over previous
//
#include <hip/hip_runtime.h>
#include <math.h>

// Problem constants (from reference)
#define N        8192
#define C        128
#define E_TOTAL  262144
#define WPR      256          // bitmap words per row = N/32
#define INV_TEMP 2.0f         // 1/0.5
#define STEPS    10
#define S_ELL    96           // max dedup'd neighbors per row (Poisson(~32) tail safe)
#define ZROW     N            // zero row in bf16 buffers (row N kept zero)
#define POS_BLOCKS 2048
#define NEG_BLOCKS 128

// ---- workspace layout (bytes), no aliasing ----
#define OFF_DINV    1024                          // float dinvs[N]   32 KB
#define OFF_CNT     (OFF_DINV + 32768)            // int   cnt[N]     32 KB
#define OFF_PPOS    (OFF_CNT + 32768)             // float ppos[2048]
#define OFF_PNEG    (OFF_PPOS + POS_BLOCKS * 4)   // float pneg[128]
#define OFF_ELL     (OFF_PNEG + 1024)             // int   ellc[N*96] 3 MB
#define OFF_BITMAP  (OFF_ELL + N * S_ELL * 4)     // 8 MB (zeroed each call)
#define BITMAP_BYTES (N * WPR * 4)
#define OFF_BUFA    (OFF_BITMAP + BITMAP_BYTES)   // bf16 (N+1)*C  (row N zeroed)
#define OFF_BUFB    (OFF_BUFA + (N + 1) * C * 2)  // bf16 (N+1)*C  (row N zeroed)

typedef unsigned int   uint;
typedef unsigned short ushort;

__device__ __forceinline__ float bflo(uint u) { return __uint_as_float(u << 16); }
__device__ __forceinline__ float bfhi(uint u) { return __uint_as_float(u & 0xffff0000u); }
__device__ __forceinline__ ushort f2bf(float f) {   // RNE
    uint u = __float_as_uint(f);
    return (ushort)((u + 0x7fffu + ((u >> 16) & 1u)) >> 16);
}
__device__ __forceinline__ float dot_u(uint a, uint b) {
    return bflo(a) * bflo(b) + bfhi(a) * bfhi(b);
}
__device__ __forceinline__ float log_sigmoid(float z) {
    return fminf(z, 0.0f) - log1pf(expf(-fabsf(z)));
}

__global__ void scatter_edges_kernel(const int* __restrict__ ei,
                                     unsigned int* __restrict__ bm) {
    int e = blockIdx.x * blockDim.x + threadIdx.x;
    if (e >= E_TOTAL) return;
    int s = ei[e];
    int t = ei[E_TOTAL + e];
    atomicOr(&bm[s * WPR + (t >> 5)], 1u << (t & 31));
}

// One-time: bitmap -> ELL col list (ZROW-padded to x8) + true cnt + d^-1/2
__global__ void build_ell_kernel(const unsigned int* __restrict__ bm,
                                 int* __restrict__ cnt,
                                 int* __restrict__ ellc,
                                 float* __restrict__ dinvs) {
    int row = blockIdx.x;
    int lane = threadIdx.x;  // one wave; each lane owns 4 consecutive words
    const unsigned int* p = bm + row * WPR;
    unsigned int w[4];
    int c = 0;
    for (int i = 0; i < 4; ++i) { w[i] = p[lane * 4 + i]; c += __popc(w[i]); }
    int inc = c;
    for (int off = 1; off < 64; off <<= 1) {
        int v = __shfl_up(inc, off, 64);
        if (lane >= off) inc += v;
    }
    int pos = inc - c;
    int total = __shfl(inc, 63, 64);
    for (int i = 0; i < 4; ++i) {
        unsigned int word = w[i];
        int jbase = (lane * 4 + i) << 5;
        while (word) {
            int b = __ffs(word) - 1;
            word &= word - 1;
            if (pos < S_ELL) ellc[row * S_ELL + pos] = jbase + b;
            ++pos;
        }
    }
    int ncap = (total < S_ELL) ? total : S_ELL;
    int npad = (ncap + 7) & ~7;        // <= 96
    if (lane < npad - ncap)            // pad with pointer to the zero row
        ellc[row * S_ELL + ncap + lane] = ZROW;
    if (lane == 0) {
        cnt[row] = ncap;
        dinvs[row] = rsqrtf((float)total);   // deg >= 1 (self-loops)
    }
}

// One diffusion step: y[row,:] = sc[row] * sum_{j in adj(row)} w_j * x[j,:]
// first: x is fp32 input, gather weight = dinvs[j]; else bf16, weight = 1.
// Writer scale: last ? d^-1/2 : 1/deg.
// 256 threads = 4 waves = 4 rows/block; quarter-wave per neighbor slot,
// 16 lanes x 16B cover one neighbor row.
__global__ __launch_bounds__(256) void spmm_step_kernel(
        const int* __restrict__ cnt, const int* __restrict__ ellc,
        const float* __restrict__ dinvs, const void* __restrict__ xin,
        ushort* __restrict__ y, int first, int last) {
    __shared__ int   scol[4 * S_ELL];
    __shared__ int   sn[4];
    __shared__ float ssc[4];
    const int tid  = threadIdx.x;
    const int wid  = tid >> 6;
    const int lane = tid & 63;
    const int qw   = lane >> 4;
    const int l16  = lane & 15;

    // stage this block's 4 rows of ELL cols (384 ints) with a strided loop
    for (int i = tid; i < 4 * S_ELL; i += 256)
        scol[i] = ellc[blockIdx.x * 4 * S_ELL + i];
    if (tid < 4) {
        int row = blockIdx.x * 4 + tid;
        sn[tid] = cnt[row];
        float ds = dinvs[row];
        ssc[tid] = last ? ds : ds * ds;
    }
    __syncthreads();

    int row = blockIdx.x * 4 + wid;
    int n = sn[wid];
    const int* cr = scol + wid * S_ELL;
    float a0=0.f,a1=0.f,a2=0.f,a3=0.f,a4=0.f,a5=0.f,a6=0.f,a7=0.f;
    if (first) {
        const float* x = (const float*)xin;
        for (int k = 0; k < n; k += 8) {
            int i0 = k + qw, i1 = k + 4 + qw;
            int   c0 = (i0 < n) ? cr[i0] : row;
            int   c1 = (i1 < n) ? cr[i1] : row;
            float w0 = (i0 < n) ? dinvs[c0] : 0.0f;
            float w1 = (i1 < n) ? dinvs[c1] : 0.0f;
            const float* r0 = x + c0 * C + l16 * 8;
            const float* r1 = x + c1 * C + l16 * 8;
            float4 ua = *(const float4*)r0, ub = *(const float4*)(r0 + 4);
            float4 va = *(const float4*)r1, vb = *(const float4*)(r1 + 4);
            a0 += w0 * ua.x + w1 * va.x;  a1 += w0 * ua.y + w1 * va.y;
            a2 += w0 * ua.z + w1 * va.z;  a3 += w0 * ua.w + w1 * va.w;
            a4 += w0 * ub.x + w1 * vb.x;  a5 += w0 * ub.y + w1 * vb.y;
            a6 += w0 * ub.z + w1 * vb.z;  a7 += w0 * ub.w + w1 * vb.w;
        }
    } else {
        const ushort* x = (const ushort*)xin;
        int npad = (n + 7) & ~7;   // ellc ZROW-padded; row ZROW is zero
        for (int k = 0; k < npad; k += 8) {
            int c0 = cr[k + qw];
            int c1 = cr[k + 4 + qw];
            uint4 u0 = *(const uint4*)(x + c0 * C + l16 * 8);
            uint4 u1 = *(const uint4*)(x + c1 * C + l16 * 8);
            a0 += bflo(u0.x) + bflo(u1.x);  a1 += bfhi(u0.x) + bfhi(u1.x);
            a2 += bflo(u0.y) + bflo(u1.y);  a3 += bfhi(u0.y) + bfhi(u1.y);
            a4 += bflo(u0.z) + bflo(u1.z);  a5 += bfhi(u0.z) + bfhi(u1.z);
            a6 += bflo(u0.w) + bflo(u1.w);  a7 += bfhi(u0.w) + bfhi(u1.w);
        }
    }
    a0 += __shfl_xor(a0, 16, 64); a0 += __shfl_xor(a0, 32, 64);
    a1 += __shfl_xor(a1, 16, 64); a1 += __shfl_xor(a1, 32, 64);
    a2 += __shfl_xor(a2, 16, 64); a2 += __shfl_xor(a2, 32, 64);
    a3 += __shfl_xor(a3, 16, 64); a3 += __shfl_xor(a3, 32, 64);
    a4 += __shfl_xor(a4, 16, 64); a4 += __shfl_xor(a4, 32, 64);
    a5 += __shfl_xor(a5, 16, 64); a5 += __shfl_xor(a5, 32, 64);
    a6 += __shfl_xor(a6, 16, 64); a6 += __shfl_xor(a6, 32, 64);
    a7 += __shfl_xor(a7, 16, 64); a7 += __shfl_xor(a7, 32, 64);
    if (qw == 0) {
        float sc = ssc[wid];
        uint4 o;
        o.x = (uint)f2bf(a0 * sc) | ((uint)f2bf(a1 * sc) << 16);
        o.y = (uint)f2bf(a2 * sc) | ((uint)f2bf(a3 * sc) << 16);
        o.z = (uint)f2bf(a4 * sc) | ((uint)f2bf(a5 * sc) << 16);
        o.w = (uint)f2bf(a6 * sc) | ((uint)f2bf(a7 * sc) << 16);
        *(uint4*)(y + row * C + l16 * 8) = o;
    }
}

// Merged pos+neg loss: blocks [0,POS_BLOCKS) do pos edges, rest do neg rows.
__global__ void loss_kernel(const ushort* __restrict__ x,
                            const int* __restrict__ ei,
                            const int* __restrict__ ridx,
                            float* __restrict__ ppos,
                            float* __restrict__ pneg) {
    __shared__ float wsum[4];
    int lane = threadIdx.x & 63;
    int g    = lane >> 2;   // 16 items per wave-iteration
    int q    = lane & 3;    // 4 lanes per item, 32 channels each
    float sum = 0.0f;
    if (blockIdx.x < POS_BLOCKS) {
        int wave = (blockIdx.x * blockDim.x + threadIdx.x) >> 6;
        int nwaves = (POS_BLOCKS * 256) >> 6;
        for (int base = wave * 16; base < E_TOTAL; base += nwaves * 16) {
            int e = base + g;
            int s = ei[e];
            int t = ei[E_TOTAL + e];
            const uint4* ps = (const uint4*)(x + s * C + q * 32);
            const uint4* pt = (const uint4*)(x + t * C + q * 32);
            uint4 s0 = ps[0], s1 = ps[1], s2 = ps[2], s3 = ps[3];
            uint4 t0 = pt[0], t1 = pt[1], t2 = pt[2], t3 = pt[3];
            float p = dot_u(s0.x, t0.x) + dot_u(s0.y, t0.y) + dot_u(s0.z, t0.z) + dot_u(s0.w, t0.w)
                    + dot_u(s1.x, t1.x) + dot_u(s1.y, t1.y) + dot_u(s1.z, t1.z) + dot_u(s1.w, t1.w)
                    + dot_u(s2.x, t2.x) + dot_u(s2.y, t2.y) + dot_u(s2.z, t2.z) + dot_u(s2.w, t2.w)
                    + dot_u(s3.x, t3.x) + dot_u(s3.y, t3.y) + dot_u(s3.z, t3.z) + dot_u(s3.w, t3.w);
            p += __shfl_xor(p, 1, 64);
            p += __shfl_xor(p, 2, 64);
            if (q == 0) sum += log_sigmoid(p * INV_TEMP);
        }
    } else {
        int bi = blockIdx.x - POS_BLOCKS;
        int wave = (bi * blockDim.x + threadIdx.x) >> 6;
        int nwaves = (NEG_BLOCKS * 256) >> 6;
        for (int base = wave * 16; base < N; base += nwaves * 16) {
            int i = base + g;
            int t = ridx[i];
            const uint4* ps = (const uint4*)(x + i * C + q * 32);
            const uint4* pt = (const uint4*)(x + t * C + q * 32);
            uint4 s0 = ps[0], s1 = ps[1], s2 = ps[2], s3 = ps[3];
            uint4 t0 = pt[0], t1 = pt[1], t2 = pt[2], t3 = pt[3];
            float p = dot_u(s0.x, t0.x) + dot_u(s0.y, t0.y) + dot_u(s0.z, t0.z) + dot_u(s0.w, t0.w)
                    + dot_u(s1.x, t1.x) + dot_u(s1.y, t1.y) + dot_u(s1.z, t1.z) + dot_u(s1.w, t1.w)
                    + dot_u(s2.x, t2.x) + dot_u(s2.y, t2.y) + dot_u(s2.z, t2.z) + dot_u(s2.w, t2.w)
                    + dot_u(s3.x, t3.x) + dot_u(s3.y, t3.y) + dot_u(s3.z, t3.z) + dot_u(s3.w, t3.w);
            p += __shfl_xor(p, 1, 64);
            p += __shfl_xor(p, 2, 64);
            if (q == 0) sum += log_sigmoid(-p * INV_TEMP);
        }
    }
    sum += __shfl_xor(sum, 4, 64);
    sum += __shfl_xor(sum, 8, 64);
    sum += __shfl_xor(sum, 16, 64);
    sum += __shfl_xor(sum, 32, 64);
    if (lane == 0) wsum[threadIdx.x >> 6] = sum;
    __syncthreads();
    if (threadIdx.x == 0) {
        float v = (wsum[0] + wsum[1]) + (wsum[2] + wsum[3]);
        if (blockIdx.x < POS_BLOCKS) ppos[blockIdx.x] = v;
        else                         pneg[blockIdx.x - POS_BLOCKS] = v;
    }
}

__global__ void finalize_kernel(const float* __restrict__ ppos,
                                const float* __restrict__ pneg,
                                float* __restrict__ out) {
    __shared__ float red[256];
    int t = threadIdx.x;
    float s = 0.0f;
    for (int i = t; i < POS_BLOCKS; i += 256) s += ppos[i];
    float sn = (t < NEG_BLOCKS) ? pneg[t] : 0.0f;
    red[t] = s * (-1.0f / (float)E_TOTAL) + sn * (-1.0f / (float)N);
    __syncthreads();
    for (int off = 128; off > 0; off >>= 1) {
        if (t < off) red[t] += red[t + off];
        __syncthreads();
    }
    if (t == 0) out[0] = red[0];
}

extern "C" void kernel_launch(void* const* d_in, const int* in_sizes, int n_in,
                              void* d_out, int out_size, void* d_ws, size_t ws_size,
                              hipStream_t stream) {
    (void)in_sizes; (void)n_in; (void)out_size; (void)ws_size;

    const float* emb_in = (const float*)d_in[0];
    const int*   ei     = (const int*)d_in[1];   // (2, E) flattened: src then dst
    const int*   ridx   = (const int*)d_in[2];
    float* out = (float*)d_out;

    char* ws = (char*)d_ws;
    float*        dinvs = (float*)(ws + OFF_DINV);
    int*          cnt   = (int*)(ws + OFF_CNT);
    float*        ppos  = (float*)(ws + OFF_PPOS);
    float*        pneg  = (float*)(ws + OFF_PNEG);
    int*          ellc  = (int*)(ws + OFF_ELL);
    unsigned int* bm    = (unsigned int*)(ws + OFF_BITMAP);
    ushort*       bufA  = (ushort*)(ws + OFF_BUFA);
    ushort*       bufB  = (ushort*)(ws + OFF_BUFB);
    ushort*       buf[2] = {bufA, bufB};

    hipMemsetAsync(bm, 0, BITMAP_BYTES, stream);
    // keep row ZROW of both bf16 buffers zero (ws is poisoned each call)
    hipMemsetAsync(bufA + (size_t)ZROW * C, 0, C * 2, stream);
    hipMemsetAsync(bufB + (size_t)ZROW * C, 0, C * 2, stream);

    scatter_edges_kernel<<<E_TOTAL / 256, 256, 0, stream>>>(ei, bm);
    build_ell_kernel<<<N, 64, 0, stream>>>(bm, cnt, ellc, dinvs);

    // 10 diffusion steps; step 0 reads the pristine fp32 input
    for (int s = 0; s < STEPS; ++s) {
        const void* xs = (s == 0) ? (const void*)emb_in : (const void*)buf[s & 1];
        ushort* yd = buf[(s + 1) & 1];
        spmm_step_kernel<<<N / 4, 256, 0, stream>>>(cnt, ellc, dinvs, xs, yd,
                                                    s == 0 ? 1 : 0,
                                                    s == STEPS - 1 ? 1 : 0);
    }
    const ushort* emb = buf[STEPS & 1];

    loss_kernel<<<POS_BLOCKS + NEG_BLOCKS, 256, 0, stream>>>(emb, ei, ridx, ppos, pneg);
    finalize_kernel<<<1, 256, 0, stream>>>(ppos, pneg, out);
}

// Round 11
// 178.951 us; speedup vs baseline: 3.5013x; 1.0149x over previous
//
#include <hip/hip_runtime.h>
#include <math.h>

// Problem constants (from reference)
#define N        8192
#define C        128
#define E_TOTAL  262144
#define WPR      256          // bitmap words per row = N/32
#define INV_TEMP 2.0f         // 1/0.5
#define STEPS    10
#define S_ELL    96           // max dedup'd neighbors per row (Poisson(~32) tail safe)
#define ZROW     N            // zero row in bf16 buffers (row N kept zero)
#define POS_BLOCKS 2048
#define NEG_BLOCKS 128

// ---- workspace layout (bytes), no aliasing ----
#define OFF_DINV    1024                          // float dinvs[N]   32 KB
#define OFF_CNT     (OFF_DINV + 32768)            // int   cnt[N]     32 KB
#define OFF_PPOS    (OFF_CNT + 32768)             // float ppos[2048]
#define OFF_PNEG    (OFF_PPOS + POS_BLOCKS * 4)   // float pneg[128]
#define OFF_ELL     (OFF_PNEG + 1024)             // int   ellc[N*96] 3 MB
#define OFF_BITMAP  (OFF_ELL + N * S_ELL * 4)     // 8 MB (zeroed each call)
#define BITMAP_BYTES (N * WPR * 4)
#define OFF_BUFA    (OFF_BITMAP + BITMAP_BYTES)   // bf16 (N+1)*C  (row N zeroed)
#define OFF_BUFB    (OFF_BUFA + (N + 1) * C * 2)  // bf16 (N+1)*C  (row N zeroed)

typedef unsigned int   uint;
typedef unsigned short ushort;

__device__ __forceinline__ float bflo(uint u) { return __uint_as_float(u << 16); }
__device__ __forceinline__ float bfhi(uint u) { return __uint_as_float(u & 0xffff0000u); }
__device__ __forceinline__ ushort f2bf(float f) {   // RNE
    uint u = __float_as_uint(f);
    return (ushort)((u + 0x7fffu + ((u >> 16) & 1u)) >> 16);
}
__device__ __forceinline__ float dot_u(uint a, uint b) {
    return bflo(a) * bflo(b) + bfhi(a) * bfhi(b);
}
__device__ __forceinline__ float log_sigmoid(float z) {
    return fminf(z, 0.0f) - log1pf(expf(-fabsf(z)));
}

// Edge scatter into dedup bitmap; blocks 0/1 also zero row ZROW of the two
// bf16 ping-pong buffers (replaces two 256B memset dispatches).
__global__ void scatter_edges_kernel(const int* __restrict__ ei,
                                     unsigned int* __restrict__ bm,
                                     ushort* __restrict__ bufA,
                                     ushort* __restrict__ bufB) {
    int tid = threadIdx.x;
    if (blockIdx.x < 2 && tid < 16) {
        ushort* zr = (blockIdx.x == 0) ? bufA : bufB;
        uint4 z; z.x = 0; z.y = 0; z.z = 0; z.w = 0;
        ((uint4*)(zr + (size_t)ZROW * C))[tid] = z;
    }
    int e = blockIdx.x * blockDim.x + tid;
    if (e >= E_TOTAL) return;
    int s = ei[e];
    int t = ei[E_TOTAL + e];
    atomicOr(&bm[s * WPR + (t >> 5)], 1u << (t & 31));
}

// One-time: bitmap -> ELL col list (ZROW-padded to x8) + true cnt + d^-1/2.
// 256 threads = 4 waves = 4 independent rows per block (cuts grid 8192->2048).
__global__ void build_ell_kernel(const unsigned int* __restrict__ bm,
                                 int* __restrict__ cnt,
                                 int* __restrict__ ellc,
                                 float* __restrict__ dinvs) {
    int wid  = threadIdx.x >> 6;
    int lane = threadIdx.x & 63;  // one wave per row; lane owns 4 words
    int row  = blockIdx.x * 4 + wid;
    const unsigned int* p = bm + row * WPR;
    unsigned int w[4];
    int c = 0;
    for (int i = 0; i < 4; ++i) { w[i] = p[lane * 4 + i]; c += __popc(w[i]); }
    int inc = c;
    for (int off = 1; off < 64; off <<= 1) {
        int v = __shfl_up(inc, off, 64);
        if (lane >= off) inc += v;
    }
    int pos = inc - c;
    int total = __shfl(inc, 63, 64);
    for (int i = 0; i < 4; ++i) {
        unsigned int word = w[i];
        int jbase = (lane * 4 + i) << 5;
        while (word) {
            int b = __ffs(word) - 1;
            word &= word - 1;
            if (pos < S_ELL) ellc[row * S_ELL + pos] = jbase + b;
            ++pos;
        }
    }
    int ncap = (total < S_ELL) ? total : S_ELL;
    int npad = (ncap + 7) & ~7;        // <= 96
    if (lane < npad - ncap)            // pad with pointer to the zero row
        ellc[row * S_ELL + ncap + lane] = ZROW;
    if (lane == 0) {
        cnt[row] = ncap;
        dinvs[row] = rsqrtf((float)total);   // deg >= 1 (self-loops)
    }
}

// One diffusion step: y[row,:] = sc[row] * sum_{j in adj(row)} w_j * x[j,:]
// first: x is fp32 input, gather weight = dinvs[j]; else bf16, weight = 1.
// Writer scale: last ? d^-1/2 : 1/deg.
// 256 threads = 4 waves = 4 rows/block; quarter-wave per neighbor slot,
// 16 lanes x 16B cover one neighbor row.
__global__ __launch_bounds__(256) void spmm_step_kernel(
        const int* __restrict__ cnt, const int* __restrict__ ellc,
        const float* __restrict__ dinvs, const void* __restrict__ xin,
        ushort* __restrict__ y, int first, int last) {
    __shared__ int   scol[4 * S_ELL];
    __shared__ int   sn[4];
    __shared__ float ssc[4];
    const int tid  = threadIdx.x;
    const int wid  = tid >> 6;
    const int lane = tid & 63;
    const int qw   = lane >> 4;
    const int l16  = lane & 15;

    // stage this block's 4 rows of ELL cols (384 ints) with a strided loop
    for (int i = tid; i < 4 * S_ELL; i += 256)
        scol[i] = ellc[blockIdx.x * 4 * S_ELL + i];
    if (tid < 4) {
        int row = blockIdx.x * 4 + tid;
        sn[tid] = cnt[row];
        float ds = dinvs[row];
        ssc[tid] = last ? ds : ds * ds;
    }
    __syncthreads();

    int row = blockIdx.x * 4 + wid;
    int n = sn[wid];
    const int* cr = scol + wid * S_ELL;
    float a0=0.f,a1=0.f,a2=0.f,a3=0.f,a4=0.f,a5=0.f,a6=0.f,a7=0.f;
    if (first) {
        const float* x = (const float*)xin;
        for (int k = 0; k < n; k += 8) {
            int i0 = k + qw, i1 = k + 4 + qw;
            int   c0 = (i0 < n) ? cr[i0] : row;
            int   c1 = (i1 < n) ? cr[i1] : row;
            float w0 = (i0 < n) ? dinvs[c0] : 0.0f;
            float w1 = (i1 < n) ? dinvs[c1] : 0.0f;
            const float* r0 = x + c0 * C + l16 * 8;
            const float* r1 = x + c1 * C + l16 * 8;
            float4 ua = *(const float4*)r0, ub = *(const float4*)(r0 + 4);
            float4 va = *(const float4*)r1, vb = *(const float4*)(r1 + 4);
            a0 += w0 * ua.x + w1 * va.x;  a1 += w0 * ua.y + w1 * va.y;
            a2 += w0 * ua.z + w1 * va.z;  a3 += w0 * ua.w + w1 * va.w;
            a4 += w0 * ub.x + w1 * vb.x;  a5 += w0 * ub.y + w1 * vb.y;
            a6 += w0 * ub.z + w1 * vb.z;  a7 += w0 * ub.w + w1 * vb.w;
        }
    } else {
        const ushort* x = (const ushort*)xin;
        int npad = (n + 7) & ~7;   // ellc ZROW-padded; row ZROW is zero
        for (int k = 0; k < npad; k += 8) {
            int c0 = cr[k + qw];
            int c1 = cr[k + 4 + qw];
            uint4 u0 = *(const uint4*)(x + c0 * C + l16 * 8);
            uint4 u1 = *(const uint4*)(x + c1 * C + l16 * 8);
            a0 += bflo(u0.x) + bflo(u1.x);  a1 += bfhi(u0.x) + bfhi(u1.x);
            a2 += bflo(u0.y) + bflo(u1.y);  a3 += bfhi(u0.y) + bfhi(u1.y);
            a4 += bflo(u0.z) + bflo(u1.z);  a5 += bfhi(u0.z) + bfhi(u1.z);
            a6 += bflo(u0.w) + bflo(u1.w);  a7 += bfhi(u0.w) + bfhi(u1.w);
        }
    }
    a0 += __shfl_xor(a0, 16, 64); a0 += __shfl_xor(a0, 32, 64);
    a1 += __shfl_xor(a1, 16, 64); a1 += __shfl_xor(a1, 32, 64);
    a2 += __shfl_xor(a2, 16, 64); a2 += __shfl_xor(a2, 32, 64);
    a3 += __shfl_xor(a3, 16, 64); a3 += __shfl_xor(a3, 32, 64);
    a4 += __shfl_xor(a4, 16, 64); a4 += __shfl_xor(a4, 32, 64);
    a5 += __shfl_xor(a5, 16, 64); a5 += __shfl_xor(a5, 32, 64);
    a6 += __shfl_xor(a6, 16, 64); a6 += __shfl_xor(a6, 32, 64);
    a7 += __shfl_xor(a7, 16, 64); a7 += __shfl_xor(a7, 32, 64);
    if (qw == 0) {
        float sc = ssc[wid];
        uint4 o;
        o.x = (uint)f2bf(a0 * sc) | ((uint)f2bf(a1 * sc) << 16);
        o.y = (uint)f2bf(a2 * sc) | ((uint)f2bf(a3 * sc) << 16);
        o.z = (uint)f2bf(a4 * sc) | ((uint)f2bf(a5 * sc) << 16);
        o.w = (uint)f2bf(a6 * sc) | ((uint)f2bf(a7 * sc) << 16);
        *(uint4*)(y + row * C + l16 * 8) = o;
    }
}

// Merged pos+neg loss: blocks [0,POS_BLOCKS) do pos edges, rest do neg rows.
__global__ void loss_kernel(const ushort* __restrict__ x,
                            const int* __restrict__ ei,
                            const int* __restrict__ ridx,
                            float* __restrict__ ppos,
                            float* __restrict__ pneg) {
    __shared__ float wsum[4];
    int lane = threadIdx.x & 63;
    int g    = lane >> 2;   // 16 items per wave-iteration
    int q    = lane & 3;    // 4 lanes per item, 32 channels each
    float sum = 0.0f;
    if (blockIdx.x < POS_BLOCKS) {
        int wave = (blockIdx.x * blockDim.x + threadIdx.x) >> 6;
        int nwaves = (POS_BLOCKS * 256) >> 6;
        for (int base = wave * 16; base < E_TOTAL; base += nwaves * 16) {
            int e = base + g;
            int s = ei[e];
            int t = ei[E_TOTAL + e];
            const uint4* ps = (const uint4*)(x + s * C + q * 32);
            const uint4* pt = (const uint4*)(x + t * C + q * 32);
            uint4 s0 = ps[0], s1 = ps[1], s2 = ps[2], s3 = ps[3];
            uint4 t0 = pt[0], t1 = pt[1], t2 = pt[2], t3 = pt[3];
            float p = dot_u(s0.x, t0.x) + dot_u(s0.y, t0.y) + dot_u(s0.z, t0.z) + dot_u(s0.w, t0.w)
                    + dot_u(s1.x, t1.x) + dot_u(s1.y, t1.y) + dot_u(s1.z, t1.z) + dot_u(s1.w, t1.w)
                    + dot_u(s2.x, t2.x) + dot_u(s2.y, t2.y) + dot_u(s2.z, t2.z) + dot_u(s2.w, t2.w)
                    + dot_u(s3.x, t3.x) + dot_u(s3.y, t3.y) + dot_u(s3.z, t3.z) + dot_u(s3.w, t3.w);
            p += __shfl_xor(p, 1, 64);
            p += __shfl_xor(p, 2, 64);
            if (q == 0) sum += log_sigmoid(p * INV_TEMP);
        }
    } else {
        int bi = blockIdx.x - POS_BLOCKS;
        int wave = (bi * blockDim.x + threadIdx.x) >> 6;
        int nwaves = (NEG_BLOCKS * 256) >> 6;
        for (int base = wave * 16; base < N; base += nwaves * 16) {
            int i = base + g;
            int t = ridx[i];
            const uint4* ps = (const uint4*)(x + i * C + q * 32);
            const uint4* pt = (const uint4*)(x + t * C + q * 32);
            uint4 s0 = ps[0], s1 = ps[1], s2 = ps[2], s3 = ps[3];
            uint4 t0 = pt[0], t1 = pt[1], t2 = pt[2], t3 = pt[3];
            float p = dot_u(s0.x, t0.x) + dot_u(s0.y, t0.y) + dot_u(s0.z, t0.z) + dot_u(s0.w, t0.w)
                    + dot_u(s1.x, t1.x) + dot_u(s1.y, t1.y) + dot_u(s1.z, t1.z) + dot_u(s1.w, t1.w)
                    + dot_u(s2.x, t2.x) + dot_u(s2.y, t2.y) + dot_u(s2.z, t2.z) + dot_u(s2.w, t2.w)
                    + dot_u(s3.x, t3.x) + dot_u(s3.y, t3.y) + dot_u(s3.z, t3.z) + dot_u(s3.w, t3.w);
            p += __shfl_xor(p, 1, 64);
            p += __shfl_xor(p, 2, 64);
            if (q == 0) sum += log_sigmoid(-p * INV_TEMP);
        }
    }
    sum += __shfl_xor(sum, 4, 64);
    sum += __shfl_xor(sum, 8, 64);
    sum += __shfl_xor(sum, 16, 64);
    sum += __shfl_xor(sum, 32, 64);
    if (lane == 0) wsum[threadIdx.x >> 6] = sum;
    __syncthreads();
    if (threadIdx.x == 0) {
        float v = (wsum[0] + wsum[1]) + (wsum[2] + wsum[3]);
        if (blockIdx.x < POS_BLOCKS) ppos[blockIdx.x] = v;
        else                         pneg[blockIdx.x - POS_BLOCKS] = v;
    }
}

__global__ void finalize_kernel(const float* __restrict__ ppos,
                                const float* __restrict__ pneg,
                                float* __restrict__ out) {
    __shared__ float red[256];
    int t = threadIdx.x;
    float s = 0.0f;
    for (int i = t; i < POS_BLOCKS; i += 256) s += ppos[i];
    float sn = (t < NEG_BLOCKS) ? pneg[t] : 0.0f;
    red[t] = s * (-1.0f / (float)E_TOTAL) + sn * (-1.0f / (float)N);
    __syncthreads();
    for (int off = 128; off > 0; off >>= 1) {
        if (t < off) red[t] += red[t + off];
        __syncthreads();
    }
    if (t == 0) out[0] = red[0];
}

extern "C" void kernel_launch(void* const* d_in, const int* in_sizes, int n_in,
                              void* d_out, int out_size, void* d_ws, size_t ws_size,
                              hipStream_t stream) {
    (void)in_sizes; (void)n_in; (void)out_size; (void)ws_size;

    const float* emb_in = (const float*)d_in[0];
    const int*   ei     = (const int*)d_in[1];   // (2, E) flattened: src then dst
    const int*   ridx   = (const int*)d_in[2];
    float* out = (float*)d_out;

    char* ws = (char*)d_ws;
    float*        dinvs = (float*)(ws + OFF_DINV);
    int*          cnt   = (int*)(ws + OFF_CNT);
    float*        ppos  = (float*)(ws + OFF_PPOS);
    float*        pneg  = (float*)(ws + OFF_PNEG);
    int*          ellc  = (int*)(ws + OFF_ELL);
    unsigned int* bm    = (unsigned int*)(ws + OFF_BITMAP);
    ushort*       bufA  = (ushort*)(ws + OFF_BUFA);
    ushort*       bufB  = (ushort*)(ws + OFF_BUFB);
    ushort*       buf[2] = {bufA, bufB};

    hipMemsetAsync(bm, 0, BITMAP_BYTES, stream);

    // scatter also zeroes row ZROW of both bf16 buffers (blocks 0/1)
    scatter_edges_kernel<<<E_TOTAL / 256, 256, 0, stream>>>(ei, bm, bufA, bufB);
    build_ell_kernel<<<N / 4, 256, 0, stream>>>(bm, cnt, ellc, dinvs);

    // 10 diffusion steps; step 0 reads the pristine fp32 input
    for (int s = 0; s < STEPS; ++s) {
        const void* xs = (s == 0) ? (const void*)emb_in : (const void*)buf[s & 1];
        ushort* yd = buf[(s + 1) & 1];
        spmm_step_kernel<<<N / 4, 256, 0, stream>>>(cnt, ellc, dinvs, xs, yd,
                                                    s == 0 ? 1 : 0,
                                                    s == STEPS - 1 ? 1 : 0);
    }
    const ushort* emb = buf[STEPS & 1];

    loss_kernel<<<POS_BLOCKS + NEG_BLOCKS, 256, 0, stream>>>(emb, ei, ridx, ppos, pneg);
    finalize_kernel<<<1, 256, 0, stream>>>(ppos, pneg, out);
}